// Round 2
// baseline (35.687 us; speedup 1.0000x reference)
//
#include <hip/hip_runtime.h>
#include <hip/hip_bf16.h>

// Volterra conv (K=3, orders 1+2) as one fused bf16 MFMA GEMM:
// out[b, l, o] = sum_{c,f} A[l, c*64+f] * Wc[c*64+f, o]
//   f<9: linear patch feature xp[f]; 9<=f<54: xp[P[t]]*xp[Q[t]]*1/sqrt(45); f>=54: pad 0
// d_out memory layout = [B, L, 64] flat (reference reshape is a reinterpret); bias_w[h] (zeros).

typedef __bf16 bf16x8 __attribute__((ext_vector_type(8)));
typedef float f32x16 __attribute__((ext_vector_type(16)));

#define SCALE_Q 0.14907119849998599f  // 1/sqrt(45)

__device__ __constant__ int g_pairP[45] = {
  0,0,0,0,0,0,0,0,0,
  1,1,1,1,1,1,1,1,
  2,2,2,2,2,2,2,
  3,3,3,3,3,3,
  4,4,4,4,4,
  5,5,5,5,
  6,6,6,
  7,7,
  8};
__device__ __constant__ int g_pairQ[45] = {
  0,1,2,3,4,5,6,7,8,
  1,2,3,4,5,6,7,8,
  2,3,4,5,6,7,8,
  3,4,5,6,7,8,
  4,5,6,7,8,
  5,6,7,8,
  6,7,8,
  7,8,
  8};

union AFrag { unsigned int u[4]; bf16x8 v; };

__device__ inline unsigned int pack_bf16x2(float a, float b){
  union { __hip_bfloat16 h; unsigned short s; } ca, cb;
  ca.h = __float2bfloat16(a);
  cb.h = __float2bfloat16(b);
  return (unsigned int)ca.s | ((unsigned int)cb.s << 16);
}

// ---------------- prep: pack weights into MFMA B-fragment order ----------------
// chunk g in [0,32768): c=g>>9; inner=g&511 = (ks*2+nb)*64 + lane.
// chunk contents (8 bf16): B[k-slot = ks*16 + (lane>>5)*8 + j][n = nb*32 + (lane&31)]
__global__ __launch_bounds__(256) void volt_pack(const float* __restrict__ W1,
                                                 const float* __restrict__ W2,
                                                 __hip_bfloat16* __restrict__ Bpack){
  int g = blockIdx.x * 256 + threadIdx.x;      // 0..32767
  int c     = g >> 9;
  int inner = g & 511;
  int lane  = inner & 63;
  int ks    = inner >> 7;
  int nb    = (inner >> 6) & 1;
  int n     = nb * 32 + (lane & 31);
  int kh    = lane >> 5;
  #pragma unroll
  for (int j = 0; j < 8; ++j){
    int f = ks * 16 + kh * 8 + j;              // feature slot within channel, 0..63
    float wv = 0.0f;
    if (f < 9)       wv = W1[(c * 9 + f) * 64 + n];
    else if (f < 54){
      int t = f - 9;
      wv = SCALE_Q * W2[(c * 81 + g_pairP[t] * 9 + g_pairQ[t]) * 64 + n];
    }
    Bpack[(size_t)g * 8 + j] = __float2bfloat16(wv);
  }
}

// ---------------- main fused kernel ----------------
// grid = 256 wgs = (b in 0..3) x (h in 0..63); 256 threads = 4 waves.
// Wave kv handles channels [kv*16, kv*16+16) (K-split); all waves cover the same
// 64(w) x 64(o) output tile; partials summed via LDS at the end.
__global__ __launch_bounds__(256, 1) void volt_main(const float* __restrict__ x,
                                                    const uint4* __restrict__ Bpack,
                                                    const float* __restrict__ bias_w,
                                                    float* __restrict__ out){
  __shared__ alignas(16) char smem[65536];     // 2 x 32KB B double-buffer; reused for reduction
  const int tid  = threadIdx.x;
  const int lane = tid & 63;
  const int kv   = tid >> 6;
  const int b    = blockIdx.x >> 6;
  const int h0   = blockIdx.x & 63;

  f32x16 acc00{}, acc01{}, acc10{}, acc11{};   // [af(row32)][nb(col32)]

  // stage B slices for iteration i (channel kv*16+i for each wave) into smem+base
  auto stage = [&](int i, int base){
    #pragma unroll
    for (int j = 0; j < 8; ++j){
      int L   = j * 256 + tid;                 // 0..2047 chunks of 16B
      int kvv = L >> 9;
      int cc  = kvv * 16 + i;
      uint4 t = Bpack[cc * 512 + (L & 511)];
      *reinterpret_cast<uint4*>(smem + base + L * 16) = t;
    }
  };

  stage(0, 0);
  __syncthreads();

  constexpr int kP[45] = {
    0,0,0,0,0,0,0,0,0, 1,1,1,1,1,1,1,1, 2,2,2,2,2,2,2,
    3,3,3,3,3,3, 4,4,4,4,4, 5,5,5,5, 6,6,6, 7,7, 8};
  constexpr int kQ[45] = {
    0,1,2,3,4,5,6,7,8, 1,2,3,4,5,6,7,8, 2,3,4,5,6,7,8,
    3,4,5,6,7,8, 4,5,6,7,8, 5,6,7,8, 6,7,8, 7,8, 8};

  for (int i = 0; i < 16; ++i){
    const int buf = i & 1;
    if (i < 15) stage(i + 1, (buf ^ 1) * 32768);

    // ---- build A fragments for channel c = kv*16+i; this lane owns row w = lane ----
    const int c = kv * 16 + i;
    const float* __restrict__ xc = x + ((size_t)(b * 64 + c)) * 4096;
    float xp[9];
    {
      const int w = lane;
      #pragma unroll
      for (int dh = 0; dh < 3; ++dh){
        int hr = h0 + dh - 1;
        bool hok = (unsigned)hr < 64u;
        #pragma unroll
        for (int dw = 0; dw < 3; ++dw){
          int wc = w + dw - 1;
          float v = 0.0f;
          if (hok && ((unsigned)wc < 64u)) v = xc[hr * 64 + wc];
          xp[dh * 3 + dw] = v;
        }
      }
    }
    float pr[45];
    #pragma unroll
    for (int t = 0; t < 45; ++t) pr[t] = xp[kP[t]] * xp[kQ[t]];

    unsigned int d[32];                         // 64 bf16 slots, packed as dwords
    #pragma unroll
    for (int s = 0; s < 32; ++s){
      const int f0 = 2 * s, f1 = 2 * s + 1;
      float a  = (f0 < 9) ? xp[f0] : ((f0 < 54) ? pr[f0 - 9] : 0.0f);
      float b2 = (f1 < 9) ? xp[f1] : ((f1 < 54) ? pr[f1 - 9] : 0.0f);
      d[s] = pack_bf16x2(a, b2);
    }

    // half-exchange: lane l holds row w=l; frag a0 covers output rows 0..31 (hw row = lane&31,
    // k-half = lane>>5), frag a1 covers rows 32..63.
    //   a0: lane<32 -> own k-low (U); lane>=32 -> partner(l-32) k-high (Vx)
    //   a1: lane<32 -> partner(l+32) k-low (Ux); lane>=32 -> own k-high (V)
    AFrag a0[4], a1[4];
    const bool hi = (lane >= 32);
    #pragma unroll
    for (int ks = 0; ks < 4; ++ks){
      #pragma unroll
      for (int j = 0; j < 4; ++j){
        unsigned int U = d[ks * 8 + j], V = d[ks * 8 + 4 + j];
        unsigned int Ux = (unsigned int)__shfl_xor((int)U, 32);
        unsigned int Vx = (unsigned int)__shfl_xor((int)V, 32);
        a0[ks].u[j] = hi ? Vx : U;
        a1[ks].u[j] = hi ? V : Ux;   // FIXED (was: hi ? Ux : V)
      }
    }

    // ---- MFMA: 4 ksteps x 4 frag-MFMAs ----
    const char* bb = smem + buf * 32768 + kv * 8192;
    #pragma unroll
    for (int ks = 0; ks < 4; ++ks){
      bf16x8 b0 = *reinterpret_cast<const bf16x8*>(bb + (((ks * 2 + 0) * 64 + lane) * 16));
      bf16x8 b1 = *reinterpret_cast<const bf16x8*>(bb + (((ks * 2 + 1) * 64 + lane) * 16));
      acc00 = __builtin_amdgcn_mfma_f32_32x32x16_bf16(a0[ks].v, b0, acc00, 0, 0, 0);
      acc01 = __builtin_amdgcn_mfma_f32_32x32x16_bf16(a0[ks].v, b1, acc01, 0, 0, 0);
      acc10 = __builtin_amdgcn_mfma_f32_32x32x16_bf16(a1[ks].v, b0, acc10, 0, 0, 0);
      acc11 = __builtin_amdgcn_mfma_f32_32x32x16_bf16(a1[ks].v, b1, acc11, 0, 0, 0);
    }
    __syncthreads();   // covers B-dbuf swap and prefetch completion (full drain before barrier)
  }

  // ---- cross-wave K reduction via LDS (reuse smem) ----
  float* red = reinterpret_cast<float*>(smem);
  {
    const int colbase = lane & 31;
    const int rowadd  = 4 * (lane >> 5);
    #pragma unroll
    for (int r = 0; r < 16; ++r){
      int rl = (r & 3) + 8 * (r >> 2) + rowadd;              // 32x32 C/D layout
      red[kv * 4096 + (rl)      * 64 + colbase     ] = acc00[r];
      red[kv * 4096 + (rl)      * 64 + colbase + 32] = acc01[r];
      red[kv * 4096 + (rl + 32) * 64 + colbase     ] = acc10[r];
      red[kv * 4096 + (rl + 32) * 64 + colbase + 32] = acc11[r];
    }
  }
  __syncthreads();
  const float bias = bias_w[h0];               // out channel index == h for this wg
  float* outp = out + (size_t)b * 262144 + (size_t)h0 * 4096;
  #pragma unroll
  for (int j = 0; j < 16; ++j){
    int oidx = j * 256 + tid;                  // w*64 + o, coalesced
    float v = red[oidx] + red[4096 + oidx] + red[8192 + oidx] + red[12288 + oidx] + bias;
    outp[oidx] = v;
  }
}

extern "C" void kernel_launch(void* const* d_in, const int* in_sizes, int n_in,
                              void* d_out, int out_size, void* d_ws, size_t ws_size,
                              hipStream_t stream){
  const float* x      = (const float*)d_in[0];
  const float* W1     = (const float*)d_in[1];
  const float* W2     = (const float*)d_in[2];
  const float* bias_w = (const float*)d_in[3];
  float* out = (float*)d_out;
  __hip_bfloat16* Bpack = (__hip_bfloat16*)d_ws;   // 512 KB

  volt_pack<<<128, 256, 0, stream>>>(W1, W2, Bpack);
  volt_main<<<256, 256, 0, stream>>>(x, (const uint4*)d_ws, bias_w, out);
}

// Round 3
// 29.734 us; speedup vs baseline: 1.2002x; 1.2002x over previous
//
#include <hip/hip_runtime.h>
#include <hip/hip_bf16.h>

// Volterra conv (K=3, orders 1+2) as one fused bf16 MFMA GEMM:
// out[b, l, o] = sum_{c,f} A[l, c*64+f] * Wc[c*64+f, o]
//   f<9: linear patch feature xp[f]; 9<=f<54: xp[P[t]]*xp[Q[t]]*1/sqrt(45); f>=54: pad 0
// d_out memory layout = [B, L, 64] flat; bias indexed by h (zeros in practice).
//
// volt_main: 256 wgs = (b,h); 4 waves, K-split 16 channels each. Waves are fully
// independent in the main loop (per-wave B staging via global_load_lds into a
// private LDS dbuf slice, per-wave s_waitcnt vmcnt(0)) -- no in-loop barriers.

typedef __bf16 bf16x8 __attribute__((ext_vector_type(8)));
typedef float f32x16 __attribute__((ext_vector_type(16)));

#define SCALE_Q 0.14907119849998599f  // 1/sqrt(45)

__device__ __constant__ int g_pairP[45] = {
  0,0,0,0,0,0,0,0,0, 1,1,1,1,1,1,1,1, 2,2,2,2,2,2,2,
  3,3,3,3,3,3, 4,4,4,4,4, 5,5,5,5, 6,6,6, 7,7, 8};
__device__ __constant__ int g_pairQ[45] = {
  0,1,2,3,4,5,6,7,8, 1,2,3,4,5,6,7,8, 2,3,4,5,6,7,8,
  3,4,5,6,7,8, 4,5,6,7,8, 5,6,7,8, 6,7,8, 7,8, 8};

union AFrag { unsigned int u[4]; bf16x8 v; };

__device__ inline unsigned int pack_bf16x2(float a, float b){
  union { __hip_bfloat16 h; unsigned short s; } ca, cb;
  ca.h = __float2bfloat16(a);
  cb.h = __float2bfloat16(b);
  return (unsigned int)ca.s | ((unsigned int)cb.s << 16);
}

// half-exchange primitive: given U (own k-low dwords) and V (own k-high dwords),
// produce o0 = {U[0:31], V[0:31]} (frag rows 0..31) and o1 = {U[32:63], V[32:63]}.
__device__ inline void half_swap(unsigned int U, unsigned int V,
                                 unsigned int& o0, unsigned int& o1, int lane){
#if __has_builtin(__builtin_amdgcn_permlane32_swap)
  auto rr = __builtin_amdgcn_permlane32_swap(U, V, false, false);
  o0 = rr[0]; o1 = rr[1];
#else
  unsigned int Ux = (unsigned int)__shfl_xor((int)U, 32);
  unsigned int Vx = (unsigned int)__shfl_xor((int)V, 32);
  const bool hi = (lane >= 32);
  o0 = hi ? Vx : U;
  o1 = hi ? V : Ux;
#endif
}

// ---------------- prep: pack weights into MFMA B-fragment order ----------------
__global__ __launch_bounds__(256) void volt_pack(const float* __restrict__ W1,
                                                 const float* __restrict__ W2,
                                                 __hip_bfloat16* __restrict__ Bpack){
  int g = blockIdx.x * 256 + threadIdx.x;      // 0..32767
  int c     = g >> 9;
  int inner = g & 511;
  int lane  = inner & 63;
  int ks    = inner >> 7;
  int nb    = (inner >> 6) & 1;
  int n     = nb * 32 + (lane & 31);
  int kh    = lane >> 5;
  #pragma unroll
  for (int j = 0; j < 8; ++j){
    int f = ks * 16 + kh * 8 + j;              // feature slot within channel, 0..63
    float wv = 0.0f;
    if (f < 9)       wv = W1[(c * 9 + f) * 64 + n];
    else if (f < 54){
      int t = f - 9;
      wv = SCALE_Q * W2[(c * 81 + g_pairP[t] * 9 + g_pairQ[t]) * 64 + n];
    }
    Bpack[(size_t)g * 8 + j] = __float2bfloat16(wv);
  }
}

// ---------------- main fused kernel ----------------
__global__ __launch_bounds__(256, 1) void volt_main(const float* __restrict__ x,
                                                    const uint4* __restrict__ Bpack,
                                                    const float* __restrict__ bias_w,
                                                    float* __restrict__ out){
  __shared__ alignas(16) char smem[65536];     // 4 waves x (2 x 8KB B dbuf); reused for reduction
  const int tid  = threadIdx.x;
  const int lane = tid & 63;
  const int kv   = tid >> 6;
  const int b    = blockIdx.x >> 6;
  const int h0   = blockIdx.x & 63;

  const int hm = (h0 > 0)  ? (h0 - 1) : 0;     // clamped row indices (masked after load)
  const int hp = (h0 < 63) ? (h0 + 1) : 63;
  const float* xw = x + ((size_t)(b * 64 + kv * 16)) * 4096;  // this wave's first channel

  char* mylds = smem + kv * 16384;
  const uint4* bsrc = Bpack + (size_t)(kv * 16) * 512 + lane;

  // stage channel-i B slice (8KB) into this wave's buffer `buf` (wave-private)
  auto stageB = [&](int i, int buf){
    const uint4* s = bsrc + i * 512;
    char* dptr = mylds + buf * 8192;
    #pragma unroll
    for (int j = 0; j < 8; ++j){
      __builtin_amdgcn_global_load_lds(
        (const __attribute__((address_space(1))) void*)(const void*)(s + j * 64),
        (__attribute__((address_space(3))) void*)(void*)(dptr + j * 1024),
        16, 0, 0);
    }
  };

  // coalesced 3-row load for channel i (this lane's w column = lane)
  auto loadX = [&](int i, float (&v)[3]){
    const float* xc = xw + (size_t)i * 4096;
    v[0] = xc[hm * 64 + lane];
    v[1] = xc[h0 * 64 + lane];
    v[2] = xc[hp * 64 + lane];
  };

  constexpr int kP[45] = {
    0,0,0,0,0,0,0,0,0, 1,1,1,1,1,1,1,1, 2,2,2,2,2,2,2,
    3,3,3,3,3,3, 4,4,4,4,4, 5,5,5,5, 6,6,6, 7,7, 8};
  constexpr int kQ[45] = {
    0,1,2,3,4,5,6,7,8, 1,2,3,4,5,6,7,8, 2,3,4,5,6,7,8,
    3,4,5,6,7,8, 4,5,6,7,8, 5,6,7,8, 6,7,8, 7,8, 8};

  f32x16 acc00{}, acc01{}, acc10{}, acc11{};   // [af(row32)][nb(col32)]
  float cx[3], nx[3] = {0.f, 0.f, 0.f};

  stageB(0, 0);
  loadX(0, cx);

  #pragma unroll
  for (int i = 0; i < 16; ++i){
    const int buf = i & 1;
    // B(i) is in LDS buf, x(i) is in cx, once this wave's vmem drains:
    asm volatile("s_waitcnt vmcnt(0)" ::: "memory");

    // prefetch next channel (latency hidden under this channel's compute)
    if (i < 15){ stageB(i + 1, buf ^ 1); loadX(i + 1, nx); }

    // ---- features for this lane's row (w = lane) ----
    float xp[9];
    #pragma unroll
    for (int dh = 0; dh < 3; ++dh){
      float mid = cx[dh];
      if (dh == 0 && h0 == 0)  mid = 0.f;      // clamped row -> zero (wave-uniform)
      if (dh == 2 && h0 == 63) mid = 0.f;
      float lf = __shfl(mid, lane - 1);
      float rt = __shfl(mid, lane + 1);
      xp[dh * 3 + 0] = (lane == 0)  ? 0.f : lf;
      xp[dh * 3 + 1] = mid;
      xp[dh * 3 + 2] = (lane == 63) ? 0.f : rt;
    }
    float pr[45];
    #pragma unroll
    for (int t = 0; t < 45; ++t) pr[t] = xp[kP[t]] * xp[kQ[t]];

    unsigned int d[32];                        // 64 bf16 slots packed as dwords
    #pragma unroll
    for (int s = 0; s < 32; ++s){
      const int f0 = 2 * s, f1 = 2 * s + 1;
      float a  = (f0 < 9) ? xp[f0] : ((f0 < 54) ? pr[f0 - 9] : 0.0f);
      float b2 = (f1 < 9) ? xp[f1] : ((f1 < 54) ? pr[f1 - 9] : 0.0f);
      d[s] = pack_bf16x2(a, b2);
    }

    // ---- A-frag half-exchange (one permlane fills both frags) ----
    AFrag a0[4], a1[4];
    #pragma unroll
    for (int ks = 0; ks < 4; ++ks){
      #pragma unroll
      for (int j = 0; j < 4; ++j){
        half_swap(d[ks * 8 + j], d[ks * 8 + 4 + j], a0[ks].u[j], a1[ks].u[j], lane);
      }
    }

    // ---- MFMA: 4 ksteps x 4 frag-MFMAs from this wave's private LDS ----
    const char* bb = mylds + buf * 8192;
    #pragma unroll
    for (int ks = 0; ks < 4; ++ks){
      bf16x8 b0 = *reinterpret_cast<const bf16x8*>(bb + (((ks * 2 + 0) * 64 + lane) * 16));
      bf16x8 b1 = *reinterpret_cast<const bf16x8*>(bb + (((ks * 2 + 1) * 64 + lane) * 16));
      acc00 = __builtin_amdgcn_mfma_f32_32x32x16_bf16(a0[ks].v, b0, acc00, 0, 0, 0);
      acc01 = __builtin_amdgcn_mfma_f32_32x32x16_bf16(a0[ks].v, b1, acc01, 0, 0, 0);
      acc10 = __builtin_amdgcn_mfma_f32_32x32x16_bf16(a1[ks].v, b0, acc10, 0, 0, 0);
      acc11 = __builtin_amdgcn_mfma_f32_32x32x16_bf16(a1[ks].v, b1, acc11, 0, 0, 0);
    }

    cx[0] = nx[0]; cx[1] = nx[1]; cx[2] = nx[2];
  }

  // ---- cross-wave K reduction via LDS (reuse smem) ----
  __syncthreads();                             // all waves done with their B slices
  float* red = reinterpret_cast<float*>(smem);
  {
    const int colbase = lane & 31;
    const int rowadd  = 4 * (lane >> 5);
    #pragma unroll
    for (int r = 0; r < 16; ++r){
      int rl = (r & 3) + 8 * (r >> 2) + rowadd;              // 32x32 C/D layout
      red[kv * 4096 + (rl)      * 64 + colbase     ] = acc00[r];
      red[kv * 4096 + (rl)      * 64 + colbase + 32] = acc01[r];
      red[kv * 4096 + (rl + 32) * 64 + colbase     ] = acc10[r];
      red[kv * 4096 + (rl + 32) * 64 + colbase + 32] = acc11[r];
    }
  }
  __syncthreads();
  const float bias = bias_w[h0];
  float* outp = out + (size_t)b * 262144 + (size_t)h0 * 4096;
  #pragma unroll
  for (int j = 0; j < 16; ++j){
    int oidx = j * 256 + tid;                  // w*64 + o, coalesced
    float v = red[oidx] + red[4096 + oidx] + red[8192 + oidx] + red[12288 + oidx] + bias;
    outp[oidx] = v;
  }
}

extern "C" void kernel_launch(void* const* d_in, const int* in_sizes, int n_in,
                              void* d_out, int out_size, void* d_ws, size_t ws_size,
                              hipStream_t stream){
  const float* x      = (const float*)d_in[0];
  const float* W1     = (const float*)d_in[1];
  const float* W2     = (const float*)d_in[2];
  const float* bias_w = (const float*)d_in[3];
  float* out = (float*)d_out;
  __hip_bfloat16* Bpack = (__hip_bfloat16*)d_ws;   // 512 KB

  volt_pack<<<128, 256, 0, stream>>>(W1, W2, Bpack);
  volt_main<<<256, 256, 0, stream>>>(x, (const uint4*)d_ws, bias_w, out);
}

// Round 4
// 22.661 us; speedup vs baseline: 1.5748x; 1.3121x over previous
//
#include <hip/hip_runtime.h>
#include <hip/hip_bf16.h>

// Volterra conv (K=3, orders 1+2) as one fused bf16 MFMA GEMM:
// out[b, l, o] = sum_{c,f} A[l, c*64+f] * Wc[c*64+f, o]
//   f<9: linear xp[f]; 9<=f<54: xp[P]*xp[Q]/sqrt(45); f>=54: 0-pad
// Output-layout identity (verified passing r2/r3): flat out = b*262144 + h_pix*4096
// + w_pix*64 + o  corresponds to ref out[b, c=h_pix, h=w_pix, w=o] + bias[h_pix].
//
// volt_main: grid 256 = (b,h_pix); 512 threads = 8 waves, K-split 8 channels/wave.
// B fragments are loaded REGISTER-DIRECT from Bpack (layout = per-lane frag order,
// coalesced uint4), double-buffered in regs; no LDS in the main loop, no barriers.
// LDS only for the final 8-way cross-wave K reduction.

typedef __bf16 bf16x8 __attribute__((ext_vector_type(8)));
typedef float f32x16 __attribute__((ext_vector_type(16)));

#define SCALE_Q 0.14907119849998599f  // 1/sqrt(45)

__device__ __constant__ int g_pairP[45] = {
  0,0,0,0,0,0,0,0,0, 1,1,1,1,1,1,1,1, 2,2,2,2,2,2,2,
  3,3,3,3,3,3, 4,4,4,4,4, 5,5,5,5, 6,6,6, 7,7, 8};
__device__ __constant__ int g_pairQ[45] = {
  0,1,2,3,4,5,6,7,8, 1,2,3,4,5,6,7,8, 2,3,4,5,6,7,8,
  3,4,5,6,7,8, 4,5,6,7,8, 5,6,7,8, 6,7,8, 7,8, 8};

union AFrag { unsigned int u[4]; bf16x8 v; };
union BFrag { uint4 q; bf16x8 v; };

__device__ inline unsigned int pack_bf16x2(float a, float b){
  union { __hip_bfloat16 h; unsigned short s; } ca, cb;
  ca.h = __float2bfloat16(a);
  cb.h = __float2bfloat16(b);
  return (unsigned int)ca.s | ((unsigned int)cb.s << 16);
}

// half-exchange: U = own k-low dword, V = own k-high dword ->
// o0 = frag word for output rows 0..31, o1 = for rows 32..63.
__device__ inline void half_swap(unsigned int U, unsigned int V,
                                 unsigned int& o0, unsigned int& o1, int lane){
#if __has_builtin(__builtin_amdgcn_permlane32_swap)
  auto rr = __builtin_amdgcn_permlane32_swap(U, V, false, false);
  o0 = rr[0]; o1 = rr[1];
#else
  unsigned int Ux = (unsigned int)__shfl_xor((int)U, 32);
  unsigned int Vx = (unsigned int)__shfl_xor((int)V, 32);
  const bool hi = (lane >= 32);
  o0 = hi ? Vx : U;
  o1 = hi ? V : Ux;
#endif
}

// ---------------- prep: pack weights into MFMA B-fragment order ----------------
// chunk g in [0,32768): c=g>>9; inner=g&511 = (ks*2+nb)*64 + lane.
// chunk (8 bf16) = B[k-slot = ks*16 + (lane>>5)*8 + j][n = nb*32 + (lane&31)]
__global__ __launch_bounds__(256) void volt_pack(const float* __restrict__ W1,
                                                 const float* __restrict__ W2,
                                                 __hip_bfloat16* __restrict__ Bpack){
  int g = blockIdx.x * 256 + threadIdx.x;      // 0..32767
  int c     = g >> 9;
  int inner = g & 511;
  int lane  = inner & 63;
  int ks    = inner >> 7;
  int nb    = (inner >> 6) & 1;
  int n     = nb * 32 + (lane & 31);
  int kh    = lane >> 5;
  #pragma unroll
  for (int j = 0; j < 8; ++j){
    int f = ks * 16 + kh * 8 + j;              // feature slot within channel
    float wv = 0.0f;
    if (f < 9)       wv = W1[(c * 9 + f) * 64 + n];
    else if (f < 54){
      int t = f - 9;
      wv = SCALE_Q * W2[(c * 81 + g_pairP[t] * 9 + g_pairQ[t]) * 64 + n];
    }
    Bpack[(size_t)g * 8 + j] = __float2bfloat16(wv);
  }
}

// ---------------- main fused kernel ----------------
__global__ __launch_bounds__(512, 2) void volt_main(const float* __restrict__ x,
                                                    const uint4* __restrict__ Bpack,
                                                    const float* __restrict__ bias_w,
                                                    float* __restrict__ out){
  __shared__ float red[8 * 4096];              // 128 KB: per-wave partial C tiles
  const int tid  = threadIdx.x;
  const int lane = tid & 63;
  const int kv   = tid >> 6;                   // wave id 0..7, channels kv*8..kv*8+7
  const int b    = blockIdx.x >> 6;
  const int h0   = blockIdx.x & 63;

  const int hm = (h0 > 0)  ? (h0 - 1) : 0;     // clamped; masked to 0 after load
  const int hp = (h0 < 63) ? (h0 + 1) : 63;
  const float* xw = x + ((size_t)(b * 64 + kv * 8)) * 4096;
  const uint4* bsrc = Bpack + (size_t)(kv * 8) * 512 + lane;

  constexpr int kP[45] = {
    0,0,0,0,0,0,0,0,0, 1,1,1,1,1,1,1,1, 2,2,2,2,2,2,2,
    3,3,3,3,3,3, 4,4,4,4,4, 5,5,5,5, 6,6,6, 7,7, 8};
  constexpr int kQ[45] = {
    0,1,2,3,4,5,6,7,8, 1,2,3,4,5,6,7,8, 2,3,4,5,6,7,8,
    3,4,5,6,7,8, 4,5,6,7,8, 5,6,7,8, 6,7,8, 7,8, 8};

  f32x16 acc00{}, acc01{}, acc10{}, acc11{};   // [row-half][col-half]

  // register-resident B (current channel) + x rows (current channel)
  BFrag curB[8];
  float cx[3];
  #pragma unroll
  for (int j = 0; j < 8; ++j) curB[j].q = bsrc[j * 64];
  cx[0] = xw[hm * 64 + lane];
  cx[1] = xw[h0 * 64 + lane];
  cx[2] = xw[hp * 64 + lane];

  #pragma unroll
  for (int i = 0; i < 8; ++i){                 // full unroll: all indexing static
    BFrag nxtB[8];
    float nx2[3];
    if (i < 7){                                // issue prefetch before any waits
      const uint4* s = bsrc + (size_t)(i + 1) * 512;
      #pragma unroll
      for (int j = 0; j < 8; ++j) nxtB[j].q = s[j * 64];
      const float* xc = xw + (size_t)(i + 1) * 4096;
      nx2[0] = xc[hm * 64 + lane];
      nx2[1] = xc[h0 * 64 + lane];
      nx2[2] = xc[hp * 64 + lane];
    }

    // ---- features for this lane's pixel (w_pix = lane) ----
    float xp[9];
    #pragma unroll
    for (int dh = 0; dh < 3; ++dh){
      float mid = cx[dh];
      if (dh == 0 && h0 == 0)  mid = 0.f;      // wave-uniform row clamp
      if (dh == 2 && h0 == 63) mid = 0.f;
      float lf = __shfl(mid, lane - 1);
      float rt = __shfl(mid, lane + 1);
      xp[dh * 3 + 0] = (lane == 0)  ? 0.f : lf;
      xp[dh * 3 + 1] = mid;
      xp[dh * 3 + 2] = (lane == 63) ? 0.f : rt;
    }
    float pr[45];
    #pragma unroll
    for (int t = 0; t < 45; ++t) pr[t] = xp[kP[t]] * xp[kQ[t]];

    unsigned int d[32];                        // 64 bf16 feature slots as dwords
    #pragma unroll
    for (int s = 0; s < 32; ++s){
      const int f0 = 2 * s, f1 = 2 * s + 1;
      float a  = (f0 < 9) ? xp[f0] : ((f0 < 54) ? pr[f0 - 9] : 0.0f);
      float b2 = (f1 < 9) ? xp[f1] : ((f1 < 54) ? pr[f1 - 9] : 0.0f);
      d[s] = pack_bf16x2(a, b2);
    }

    // ---- A-frag half-exchange ----
    AFrag a0[4], a1[4];
    #pragma unroll
    for (int ks = 0; ks < 4; ++ks){
      #pragma unroll
      for (int j = 0; j < 4; ++j){
        half_swap(d[ks * 8 + j], d[ks * 8 + 4 + j], a0[ks].u[j], a1[ks].u[j], lane);
      }
    }

    // ---- MFMA straight from register B fragments ----
    #pragma unroll
    for (int ks = 0; ks < 4; ++ks){
      acc00 = __builtin_amdgcn_mfma_f32_32x32x16_bf16(a0[ks].v, curB[ks*2+0].v, acc00, 0, 0, 0);
      acc01 = __builtin_amdgcn_mfma_f32_32x32x16_bf16(a0[ks].v, curB[ks*2+1].v, acc01, 0, 0, 0);
      acc10 = __builtin_amdgcn_mfma_f32_32x32x16_bf16(a1[ks].v, curB[ks*2+0].v, acc10, 0, 0, 0);
      acc11 = __builtin_amdgcn_mfma_f32_32x32x16_bf16(a1[ks].v, curB[ks*2+1].v, acc11, 0, 0, 0);
    }

    if (i < 7){
      #pragma unroll
      for (int j = 0; j < 8; ++j) curB[j] = nxtB[j];
      cx[0] = nx2[0]; cx[1] = nx2[1]; cx[2] = nx2[2];
    }
  }

  // ---- cross-wave K reduction via LDS (single barrier pair) ----
  {
    const int colbase = lane & 31;
    const int rowadd  = 4 * (lane >> 5);
    #pragma unroll
    for (int r = 0; r < 16; ++r){
      int rl = (r & 3) + 8 * (r >> 2) + rowadd;              // 32x32 C/D layout
      red[kv * 4096 + (rl)      * 64 + colbase     ] = acc00[r];
      red[kv * 4096 + (rl)      * 64 + colbase + 32] = acc01[r];
      red[kv * 4096 + (rl + 32) * 64 + colbase     ] = acc10[r];
      red[kv * 4096 + (rl + 32) * 64 + colbase + 32] = acc11[r];
    }
  }
  __syncthreads();
  const float bias = bias_w[h0];
  float* outp = out + (size_t)b * 262144 + (size_t)h0 * 4096;
  #pragma unroll
  for (int j = 0; j < 8; ++j){
    int oidx = j * 512 + tid;                  // w_pix*64 + o, coalesced
    float v = bias;
    #pragma unroll
    for (int kvv = 0; kvv < 8; ++kvv) v += red[kvv * 4096 + oidx];
    outp[oidx] = v;
  }
}

extern "C" void kernel_launch(void* const* d_in, const int* in_sizes, int n_in,
                              void* d_out, int out_size, void* d_ws, size_t ws_size,
                              hipStream_t stream){
  const float* x      = (const float*)d_in[0];
  const float* W1     = (const float*)d_in[1];
  const float* W2     = (const float*)d_in[2];
  const float* bias_w = (const float*)d_in[3];
  float* out = (float*)d_out;
  __hip_bfloat16* Bpack = (__hip_bfloat16*)d_ws;   // 512 KB

  volt_pack<<<128, 256, 0, stream>>>(W1, W2, Bpack);
  volt_main<<<256, 512, 0, stream>>>(x, (const uint4*)d_ws, bias_w, out);
}